// Round 6
// baseline (285.412 us; speedup 1.0000x reference)
//
#include <hip/hip_runtime.h>
#include <stdint.h>

// Problem constants
#define BB   256
#define NN   2048
#define MM   64
#define CC   512
#define OUTD 198

// Workspace layout (floats) — total 581,632 floats = 2.22 MB (< round-0 usage)
#define OS_STRIDE 200
#define OS_OFF    0                          // [B][200] raw controller outputs
#define LG_OFF    (BB * OS_STRIDE)           // [B][N] logits
#define MXP_OFF   (LG_OFF + BB * NN)         // [B][8] chunk max
#define SEP_OFF   (MXP_OFF + BB * 8)         // [B][8] chunk expsum
#define PTP_OFF   (SEP_OFF + BB * 8)         // [B][8] chunk sharpen-sum

typedef float vf4 __attribute__((ext_vector_type(4)));

__device__ __forceinline__ float softplusf(float x) {
    return x > 20.f ? x : log1pf(expf(x));
}
__device__ __forceinline__ float sigmoidf(float x) {
    return 1.f / (1.f + expf(-x));
}

// Block reductions (4 waves of 64)
__device__ __forceinline__ float bred_max(float v, float* red) {
    #pragma unroll
    for (int off = 32; off; off >>= 1) v = fmaxf(v, __shfl_down(v, off, 64));
    if ((threadIdx.x & 63) == 0) red[threadIdx.x >> 6] = v;
    __syncthreads();
    float r = fmaxf(fmaxf(red[0], red[1]), fmaxf(red[2], red[3]));
    __syncthreads();
    return r;
}
__device__ __forceinline__ float bred_sum(float v, float* red) {
    #pragma unroll
    for (int off = 32; off; off >>= 1) v += __shfl_down(v, off, 64);
    if ((threadIdx.x & 63) == 0) red[threadIdx.x >> 6] = v;
    __syncthreads();
    float r = red[0] + red[1] + red[2] + red[3];
    __syncthreads();
    return r;
}

// ---------------------------------------------------------------------------
// k_ctrl: controller matvec, fully parallel. 8 blocks/batch, 25 W-rows each.
// Grid 2048 x 256 = 8 blocks/CU, 32 waves. 8 lanes/row, shuffle reduce.
// Raw outputs os[b][r] go to ws; activations applied downstream (cheap).
// ---------------------------------------------------------------------------
__global__ __launch_bounds__(256, 8) void k_ctrl(
        const float* __restrict__ h, const float* __restrict__ Wm,
        const float* __restrict__ bias, float* __restrict__ ws) {
    __shared__ float hs[CC];
    const int b = blockIdx.x >> 3, c = blockIdx.x & 7, t = threadIdx.x;
    hs[t]       = h[(size_t)b * CC + t];
    hs[t + 256] = h[(size_t)b * CC + t + 256];
    __syncthreads();

    const int slot = t >> 3, l8 = t & 7;
    const int r = c * 25 + slot;
    if (slot < 25 && r < OUTD) {
        const float* wr = Wm + (size_t)r * CC + l8 * 64;
        const float* hp = hs + l8 * 64;
        float acc = 0.f;
        #pragma unroll
        for (int q = 0; q < 16; ++q) {
            const float4 p = *(const float4*)(wr + q * 4);
            acc += p.x * hp[q*4+0] + p.y * hp[q*4+1] + p.z * hp[q*4+2] + p.w * hp[q*4+3];
        }
        acc += __shfl_xor(acc, 1, 64);
        acc += __shfl_xor(acc, 2, 64);
        acc += __shfl_xor(acc, 4, 64);
        if (l8 == 0) ws[OS_OFF + b * OS_STRIDE + r] = acc + bias[r];
    }
}

// ---------------------------------------------------------------------------
// k_logits: content-addressing logits + PER-CHUNK softmax partials (max,
// expsum). 8 blocks/batch, 256 rows each. Grid 2048 x 256 = 8 blocks/CU.
// Normal caching loads pull `memory` into LLC for k_write's re-read.
// ---------------------------------------------------------------------------
__global__ __launch_bounds__(256, 8) void k_logits(
        const float* __restrict__ mem, float* __restrict__ ws) {
    __shared__ __align__(16) float kk[MM];
    __shared__ float sc[2];      // 0: knorm, 1: beta
    __shared__ float lgl[256];
    __shared__ float red[4];
    const int b = blockIdx.x >> 3, c = blockIdx.x & 7, t = threadIdx.x;
    const float* osb = ws + OS_OFF + (size_t)b * OS_STRIDE;

    if (t < 64) {
        const float kv = osb[t] + 1e-16f;
        kk[t] = kv;
        float ss = kv * kv;
        #pragma unroll
        for (int off = 32; off; off >>= 1) ss += __shfl_xor(ss, off, 64);
        if (t == 0) sc[0] = sqrtf(ss);
    } else if (t == 64) {
        sc[1] = softplusf(osb[64]);
    }
    __syncthreads();

    const int l = t & 15, grp = t >> 4;
    float kv0 = kk[4*l+0], kv1 = kk[4*l+1], kv2 = kk[4*l+2], kv3 = kk[4*l+3];
    const float beta = sc[1], knorm = sc[0];
    const int row0 = c * 256;
    #pragma unroll
    for (int it = 0; it < 16; ++it) {
        const int row = row0 + it * 16 + grp;
        const float4 p = *(const float4*)(mem + ((size_t)b * NN + row) * MM + 4 * l);
        const float m0 = p.x + 1e-16f, m1 = p.y + 1e-16f;
        const float m2 = p.z + 1e-16f, m3 = p.w + 1e-16f;
        float dot = m0 * kv0 + m1 * kv1 + m2 * kv2 + m3 * kv3;
        float ss  = m0 * m0 + m1 * m1 + m2 * m2 + m3 * m3;
        #pragma unroll
        for (int off = 1; off < 16; off <<= 1) {
            dot += __shfl_xor(dot, off, 64);
            ss  += __shfl_xor(ss,  off, 64);
        }
        if (l == 0) {
            const float lgv = beta * dot / fmaxf(sqrtf(ss) * knorm, 1e-8f);
            ws[LG_OFF + (size_t)b * NN + row] = lgv;
            lgl[it * 16 + grp] = lgv;
        }
    }
    __syncthreads();

    const float v  = lgl[t];
    const float mx = bred_max(v, red);
    const float se = bred_sum(expf(v - mx), red);
    if (t == 0) {
        ws[MXP_OFF + b * 8 + c] = mx;
        ws[SEP_OFF + b * 8 + c] = se;
    }
}

// ---------------------------------------------------------------------------
// k_sharp: merge softmax partials -> w_g (incl. the 2 chunk-boundary rows,
// computed locally) -> circular-shift conv -> sharpen -> UNNORMALIZED w_s
// (staged in w_out) + per-chunk sharpen-sum partial. 8 blocks/batch.
// All traffic is L2/LLC-hot (logits, w_prev chunk, partials).
// ---------------------------------------------------------------------------
__global__ __launch_bounds__(256, 8) void k_sharp(
        const float* __restrict__ w_prev, float* __restrict__ ws,
        float* __restrict__ w_out) {
    __shared__ float wgc[258];
    __shared__ float sc[7];   // 0:g 1:gamma 2:s0 3:s1 4:s2 5:mx 6:invtot
    __shared__ float red[4];
    const int b = blockIdx.x >> 3, c = blockIdx.x & 7, t = threadIdx.x;
    const float* osb = ws + OS_OFF + (size_t)b * OS_STRIDE;

    if (t == 0) {
        sc[0] = sigmoidf(osb[65]);
        sc[1] = 1.f + softplusf(osb[69]);
        const float x0 = osb[66], x1 = osb[67], x2 = osb[68];
        const float m3 = fmaxf(x0, fmaxf(x1, x2));
        const float e0 = expf(x0 - m3), e1 = expf(x1 - m3), e2 = expf(x2 - m3);
        const float i3 = 1.f / (e0 + e1 + e2);
        sc[2] = e0 * i3; sc[3] = e1 * i3; sc[4] = e2 * i3;
        float mx = -1e30f;
        #pragma unroll
        for (int j = 0; j < 8; ++j) mx = fmaxf(mx, ws[MXP_OFF + b * 8 + j]);
        float tot = 0.f;
        #pragma unroll
        for (int j = 0; j < 8; ++j)
            tot += ws[SEP_OFF + b * 8 + j] * expf(ws[MXP_OFF + b * 8 + j] - mx);
        sc[5] = mx; sc[6] = 1.f / tot;
    }
    __syncthreads();
    const float g = sc[0], gamma = sc[1];
    const float s0 = sc[2], s1 = sc[3], s2 = sc[4];
    const float mx = sc[5], invtot = sc[6];

    for (int j = t; j < 258; j += 256) {
        const int r = (c * 256 - 1 + j) & (NN - 1);
        const float wc = expf(ws[LG_OFF + (size_t)b * NN + r] - mx) * invtot;
        wgc[j] = g * wc + (1.f - g) * w_prev[(size_t)b * NN + r];
    }
    __syncthreads();

    const float wt = wgc[t] * s0 + wgc[t + 1] * s1 + wgc[t + 2] * s2;
    const float wsv = (wt > 0.f) ? exp2f(gamma * log2f(wt)) : 0.f;
    w_out[(size_t)b * NN + c * 256 + t] = wsv;     // temp, unnormalized
    const float ps = bred_sum(wsv, red);
    if (t == 0) ws[PTP_OFF + b * 8 + c] = ps;
}

// ---------------------------------------------------------------------------
// k_write: merge sharpen partials -> normalize w (rewrite w_out final) ->
// erase/add memory write for this chunk's 256 rows. 8 blocks/batch,
// 8 blocks/CU. NT stores keep mem_out from evicting LLC-resident `memory`.
// ---------------------------------------------------------------------------
__global__ __launch_bounds__(256, 8) void k_write(
        const float* __restrict__ mem, const float* __restrict__ ws,
        float* __restrict__ w_out, float* __restrict__ mem_out) {
    __shared__ float wrow[256];
    __shared__ __align__(16) float ee[MM], aa[MM];
    __shared__ float scp[1];
    const int b = blockIdx.x >> 3, c = blockIdx.x & 7, t = threadIdx.x;
    const float* osb = ws + OS_OFF + (size_t)b * OS_STRIDE;

    if (t == 0) {
        float pt = 0.f;
        #pragma unroll
        for (int j = 0; j < 8; ++j) pt += ws[PTP_OFF + b * 8 + j];
        scp[0] = 1.f / (pt + 1e-16f);
    } else if (t >= 64 && t < 128) {
        ee[t - 64] = sigmoidf(osb[70 + (t - 64)]);
    } else if (t >= 128 && t < 192) {
        aa[t - 128] = osb[134 + (t - 128)];
    }
    __syncthreads();

    const float wv = w_out[(size_t)b * NN + c * 256 + t] * scp[0];
    wrow[t] = wv;
    w_out[(size_t)b * NN + c * 256 + t] = wv;      // final w
    __syncthreads();

    const int seg = t & 15, rs = t >> 4;
    const vf4 ev = *(const vf4*)&ee[4 * seg];
    const vf4 av = *(const vf4*)&aa[4 * seg];
    const float* mb = mem + ((size_t)b * NN + c * 256) * MM + 4 * seg;
    float* ob = mem_out + ((size_t)b * NN + c * 256) * MM + 4 * seg;
    #pragma unroll 4
    for (int it = 0; it < 16; ++it) {
        const int rr = it * 16 + rs;
        const float w = wrow[rr];                   // LDS broadcast
        const float4 p = *(const float4*)(mb + (size_t)rr * MM);
        vf4 o;
        o.x = p.x * (1.f - w * ev.x) + w * av.x;
        o.y = p.y * (1.f - w * ev.y) + w * av.y;
        o.z = p.z * (1.f - w * ev.z) + w * av.z;
        o.w = p.w * (1.f - w * ev.w) + w * av.w;
        __builtin_nontemporal_store(o, (vf4*)(ob + (size_t)rr * MM));
    }
}

extern "C" void kernel_launch(void* const* d_in, const int* in_sizes, int n_in,
                              void* d_out, int out_size, void* d_ws, size_t ws_size,
                              hipStream_t stream) {
    const float* h      = (const float*)d_in[0];
    const float* w_prev = (const float*)d_in[1];
    const float* memory = (const float*)d_in[2];
    const float* W      = (const float*)d_in[3];
    const float* bias   = (const float*)d_in[4];
    float* out = (float*)d_out;
    float* ws  = (float*)d_ws;

    float* w_out   = out;                       // [B,N]
    float* mem_out = out + (size_t)BB * NN;     // [B,N,M]

    k_ctrl  <<<BB * 8, 256, 0, stream>>>(h, W, bias, ws);
    k_logits<<<BB * 8, 256, 0, stream>>>(memory, ws);
    k_sharp <<<BB * 8, 256, 0, stream>>>(w_prev, ws, w_out);
    k_write <<<BB * 8, 256, 0, stream>>>(memory, ws, w_out, mem_out);
}

// Round 7
// 272.880 us; speedup vs baseline: 1.0459x; 1.0459x over previous
//
#include <hip/hip_runtime.h>
#include <stdint.h>

// Problem constants
#define BB   256
#define NN   2048
#define MM   64
#define CC   512
#define OUTD 198

#define CHUNK_F 4096              // floats per chunk = 16 KB = 64 rows
#define NCH     32                // chunks per batch (512 KB / 16 KB)

typedef float vf4 __attribute__((ext_vector_type(4)));

__device__ __forceinline__ float softplusf(float x) {
    return x > 20.f ? x : log1pf(expf(x));
}
__device__ __forceinline__ float sigmoidf(float x) {
    return 1.f / (1.f + expf(-x));
}

// async global->LDS DMA, 16B per lane. LDS dest is wave-uniform base (+lane*16
// by HW); global src is per-lane.
__device__ __forceinline__ void dma16(const float* g, float* l) {
    __builtin_amdgcn_global_load_lds(
        (const __attribute__((address_space(1))) uint32_t*)g,
        (__attribute__((address_space(3))) uint32_t*)l, 16, 0, 0);
}

// Counted vmcnt wait: N = number of vm ops issued AFTER the op we need (vmcnt
// retires strictly in issue order on CDNA, so outstanding is a suffix).
#define WAITV(N) do { \
    asm volatile("s_waitcnt vmcnt(" #N ")" ::: "memory"); \
    __builtin_amdgcn_sched_barrier(0); \
} while (0)

// Raw barrier: waits LDS ops only; in-flight global_load_lds survive.
__device__ __forceinline__ void bar_lds() {
    asm volatile("s_waitcnt lgkmcnt(0)" ::: "memory");
    __builtin_amdgcn_sched_barrier(0);
    __builtin_amdgcn_s_barrier();
    __builtin_amdgcn_sched_barrier(0);
}

// ---------------------------------------------------------------------------
// Fused NTM write head, 4-deep continuous DMA ring. One block/batch, 16 waves.
// The ring NEVER stops: laps 0..31 stream `memory` for the logits pass, laps
// 32..63 re-stream it (LLC-hot) for the erase/add write; laps 32..35 are
// issued from inside the ph1 loop tail so they land during ph2 (softmax).
// Per-wave slices (wave stages+consumes its own 1KB of each chunk) -> no
// barriers inside streaming loops; counted vmcnt, never a mid-loop drain.
// ---------------------------------------------------------------------------
__global__ __launch_bounds__(1024, 4) void k_fused(
        const float* __restrict__ h, const float* __restrict__ Wm,
        const float* __restrict__ bias, const float* __restrict__ w_prev,
        const float* __restrict__ mem, float* __restrict__ w_out,
        float* __restrict__ mem_out) {
    __shared__ __align__(16) float stage[4][CHUNK_F];   // 64 KB DMA ring
    __shared__ float hs[CC];
    __shared__ float os[OUTD];
    __shared__ __align__(16) float kk[MM];   // k + 1e-16
    __shared__ __align__(16) float ee[MM];   // sigmoid(e)
    __shared__ __align__(16) float aa[MM];
    __shared__ float sc[8];                  // 0:beta 1:g 2:gamma 3:knorm 4..6:s
    __shared__ float lgs[NN];                // logits, later final w
    __shared__ float wg[NN];                 // gated weights
    __shared__ float wprev_s[NN];            // w_prev parked in LDS
    __shared__ float red[16];
    __shared__ float red2[16];

    const int b  = blockIdx.x;
    const int t  = threadIdx.x;
    const int ln = t & 63;                   // lane
    const int wv = t >> 6;                   // wave id (0..15)
    const int seg  = ln & 15;                // 16B segment within a row
    const int rsub = ln >> 4;                // row within wave's 4-row slice

    const float* mb = mem + (size_t)b * (NN * MM);

    // ---- prologue: plain loads first (oldest in FIFO), then DMA laps 0,1 --
    float hv = 0.f;
    if (t < CC) hv = h[(size_t)b * CC + t];
    const float wp0 = w_prev[(size_t)b * NN + t];
    const float wp1 = w_prev[(size_t)b * NN + t + 1024];
    dma16(mb + 0 * CHUNK_F + wv * 256 + ln * 4, &stage[0][wv * 256]);
    dma16(mb + 1 * CHUNK_F + wv * 256 + ln * 4, &stage[1][wv * 256]);
    if (t < CC) hs[t] = hv;                  // waits only its own (oldest) load
    wprev_s[t] = wp0;
    wprev_s[t + 1024] = wp1;
    bar_lds();

    // ---- phase 0: controller projection (198x512 matvec) -----------------
    if (t < 4 * OUTD) {                      // 4 lanes per output row
        const int row = t >> 2, l4 = t & 3;
        const float* wr = Wm + (size_t)row * CC + 4 * l4;
        float acc = 0.f;
        #pragma unroll
        for (int c = 0; c < CC; c += 16) {
            const float4 p = *(const float4*)(wr + c);
            const int hb = c + 4 * l4;
            acc += p.x * hs[hb] + p.y * hs[hb + 1] + p.z * hs[hb + 2] + p.w * hs[hb + 3];
        }
        acc += __shfl_xor(acc, 1, 64);
        acc += __shfl_xor(acc, 2, 64);
        if (l4 == 0) os[row] = acc + bias[row];
    }
    // laps 2,3 issued after the matvec's W loads (keeps ph0's W-waits from
    // serializing behind 64KB of DMA; all lanes active here)
    dma16(mb + 2 * CHUNK_F + wv * 256 + ln * 4, &stage[2][wv * 256]);
    dma16(mb + 3 * CHUNK_F + wv * 256 + ln * 4, &stage[3][wv * 256]);
    bar_lds();

    // ---- phase 0b: split + activations -----------------------------------
    if (t < 64) {
        const float kv = os[t] + 1e-16f;
        kk[t] = kv;
        float ss = kv * kv;
        #pragma unroll
        for (int off = 32; off; off >>= 1) ss += __shfl_xor(ss, off, 64);
        if (t == 0) sc[3] = sqrtf(ss);       // ||k + 1e-16||
    } else if (t < 128) {
        const int m = t - 64;
        ee[m] = sigmoidf(os[70 + m]);
        aa[m] = os[134 + m];
    } else if (t == 128) {
        sc[0] = softplusf(os[64]);           // beta
    } else if (t == 129) {
        sc[1] = sigmoidf(os[65]);            // g
    } else if (t == 130) {
        sc[2] = 1.f + softplusf(os[69]);     // gamma
    } else if (t == 131) {                   // 3-way softmax for shift weights
        const float x0 = os[66], x1 = os[67], x2 = os[68];
        const float mx = fmaxf(x0, fmaxf(x1, x2));
        const float e0 = expf(x0 - mx), e1 = expf(x1 - mx), e2 = expf(x2 - mx);
        const float inv = 1.f / (e0 + e1 + e2);
        sc[4] = e0 * inv; sc[5] = e1 * inv; sc[6] = e2 * inv;
    }
    bar_lds();

    // ---- phase 1: content logits; ring laps 4..35 issued here ------------
    // Exactly 3 laps are newer than lap c at its wait -> vmcnt(3) always.
    // Laps 32..35 re-read chunks 0..3 (LLC-hot) = ph3's prefetch.
    float wmax = -1e30f;
    {
        const float kv0 = kk[4 * seg + 0], kv1 = kk[4 * seg + 1];
        const float kv2 = kk[4 * seg + 2], kv3 = kk[4 * seg + 3];
        const float beta = sc[0], knorm = sc[3];
        for (int c = 0; c < NCH; ++c) {
            WAITV(3);
            const float4 p = *(const float4*)&stage[c & 3][wv * 256 + ln * 4];
            const float m0 = p.x + 1e-16f, m1 = p.y + 1e-16f;
            const float m2 = p.z + 1e-16f, m3 = p.w + 1e-16f;
            float dot = m0 * kv0 + m1 * kv1 + m2 * kv2 + m3 * kv3;
            float ss  = m0 * m0 + m1 * m1 + m2 * m2 + m3 * m3;
            #pragma unroll
            for (int off = 1; off < 16; off <<= 1) {
                dot += __shfl_xor(dot, off, 64);
                ss  += __shfl_xor(ss,  off, 64);
            }
            const float lgv = beta * dot / fmaxf(sqrtf(ss) * knorm, 1e-8f);
            wmax = fmaxf(wmax, lgv);
            if (seg == 0) lgs[c * 64 + wv * 4 + rsub] = lgv;
            // lap c+4 overwrites the slot just consumed (p already in regs)
            dma16(mb + (size_t)((c + 4) & 31) * CHUNK_F + wv * 256 + ln * 4,
                  &stage[(c + 4) & 3][wv * 256]);
        }
    }
    // fold per-wave running max (lanes cover rows rsub of each chunk)
    wmax = fmaxf(wmax, __shfl_xor(wmax, 16, 64));
    wmax = fmaxf(wmax, __shfl_xor(wmax, 32, 64));
    if (ln == 0) red[wv] = wmax;
    bar_lds();                                            // A

    // ---- phase 2: softmax -> gate -> shift -> sharpen -> normalize -------
    const float g = sc[1], gamma = sc[2];
    const float s0 = sc[4], s1 = sc[5], s2 = sc[6];

    float mx = red[0];
    #pragma unroll
    for (int i = 1; i < 16; ++i) mx = fmaxf(mx, red[i]);
    float v0 = expf(lgs[t] - mx), v1 = expf(lgs[t + 1024] - mx);
    float lsum = v0 + v1;
    #pragma unroll
    for (int off = 32; off; off >>= 1) lsum += __shfl_xor(lsum, off, 64);
    if (ln == 0) red2[wv] = lsum;
    bar_lds();                                            // B
    float tot = 0.f;
    #pragma unroll
    for (int i = 0; i < 16; ++i) tot += red2[i];
    const float inv = 1.f / tot;

    wg[t]        = g * (v0 * inv) + (1.f - g) * wprev_s[t];
    wg[t + 1024] = g * (v1 * inv) + (1.f - g) * wprev_s[t + 1024];
    bar_lds();                                            // C

    float ws0, ws1;
    {
        const int n0 = t;
        const float wt0 = wg[(n0 + NN - 1) & (NN - 1)] * s0 + wg[n0] * s1
                        + wg[(n0 + 1) & (NN - 1)] * s2;
        ws0 = (wt0 > 0.f) ? exp2f(gamma * log2f(wt0)) : 0.f;
        const int n1 = t + 1024;
        const float wt1 = wg[(n1 - 1) & (NN - 1)] * s0 + wg[n1] * s1
                        + wg[(n1 + 1) & (NN - 1)] * s2;
        ws1 = (wt1 > 0.f) ? exp2f(gamma * log2f(wt1)) : 0.f;
    }
    float psum = ws0 + ws1;
    #pragma unroll
    for (int off = 32; off; off >>= 1) psum += __shfl_xor(psum, off, 64);
    if (ln == 0) red[wv] = psum;
    bar_lds();                                            // D
    float ptot = 0.f;
    #pragma unroll
    for (int i = 0; i < 16; ++i) ptot += red[i];
    const float invp = 1.f / (ptot + 1e-16f);

    const float wf0 = ws0 * invp, wf1 = ws1 * invp;
    lgs[t] = wf0;                              // reuse lgs as final-w buffer
    lgs[t + 1024] = wf1;
    w_out[(size_t)b * NN + t] = wf0;           // 2 global stores (counted below)
    w_out[(size_t)b * NN + t + 1024] = wf1;
    bar_lds();                                            // E

    // ---- phase 3: erase/add write; ring laps 36..63 issued here ----------
    // In-order vmcnt counts (ops newer than lap 32+c at its wait):
    //   c=0:5  c=1:6  c=2:7  c=3:8  c=4..28:6  c=29:5  c=30:4  c=31:3
    // (laps 33+c..35+c, the 2 w_out stores for c<=3, NT stores c-3..c-1)
    {
        const vf4 ev = *(const vf4*)&ee[4 * seg];
        const vf4 av = *(const vf4*)&aa[4 * seg];
        float* ob = mem_out + (size_t)b * (NN * MM);
        #pragma unroll
        for (int c = 0; c < NCH; ++c) {
            if      (c == 0) WAITV(5);
            else if (c == 1) WAITV(6);
            else if (c == 2) WAITV(7);
            else if (c == 3) WAITV(8);
            else if (c == 29) WAITV(5);
            else if (c == 30) WAITV(4);
            else if (c == 31) WAITV(3);
            else             WAITV(6);
            const float wq = lgs[c * 64 + wv * 4 + rsub];   // LDS broadcast
            const float4 p = *(const float4*)&stage[c & 3][wv * 256 + ln * 4];
            vf4 o;
            o.x = p.x * (1.f - wq * ev.x) + wq * av.x;
            o.y = p.y * (1.f - wq * ev.y) + wq * av.y;
            o.z = p.z * (1.f - wq * ev.z) + wq * av.z;
            o.w = p.w * (1.f - wq * ev.w) + wq * av.w;
            __builtin_nontemporal_store(
                o, (vf4*)(ob + (size_t)c * CHUNK_F + wv * 256 + ln * 4));
            if (c < NCH - 4)
                dma16(mb + (size_t)(c + 4) * CHUNK_F + wv * 256 + ln * 4,
                      &stage[(c + 4) & 3][wv * 256]);
        }
    }
}

extern "C" void kernel_launch(void* const* d_in, const int* in_sizes, int n_in,
                              void* d_out, int out_size, void* d_ws, size_t ws_size,
                              hipStream_t stream) {
    const float* h      = (const float*)d_in[0];
    const float* w_prev = (const float*)d_in[1];
    const float* memory = (const float*)d_in[2];
    const float* W      = (const float*)d_in[3];
    const float* bias   = (const float*)d_in[4];
    float* out = (float*)d_out;

    float* w_out   = out;                       // [B,N]
    float* mem_out = out + (size_t)BB * NN;     // [B,N,M]

    k_fused<<<BB, 1024, 0, stream>>>(h, W, bias, w_prev, memory, w_out, mem_out);
}